// Round 7
// baseline (181.827 us; speedup 1.0000x reference)
//
#include <hip/hip_runtime.h>
#include <hip/hip_bf16.h>

// Problem constants
#define BB 512   // batch
#define SS 96    // seq len
#define NN 64    // nodes
#define HH 512   // hidden
#define EE 512   // edges per graph

typedef __attribute__((ext_vector_type(8))) short short8;   // 8 bf16 (4 VGPRs)
typedef __attribute__((ext_vector_type(4))) float f32x4;    // MFMA acc
typedef unsigned short u16;

__device__ __forceinline__ u16 f2bf(float f) {
    union { float f; unsigned u; } v; v.f = f;
    return (u16)((v.u + 0x7FFFu + ((v.u >> 16) & 1u)) >> 16);   // RNE
}
__device__ __forceinline__ short8 ld8bf(const u16* p) { return *(const short8*)p; }
__device__ __forceinline__ short8 cvt8(const float* p) {       // 8 fp32 -> bf16 frag
    float4 a = *(const float4*)p, b = *(const float4*)(p + 4);
    short8 r;
    r[0] = (short)f2bf(a.x); r[1] = (short)f2bf(a.y);
    r[2] = (short)f2bf(a.z); r[3] = (short)f2bf(a.w);
    r[4] = (short)f2bf(b.x); r[5] = (short)f2bf(b.y);
    r[6] = (short)f2bf(b.z); r[7] = (short)f2bf(b.w);
    return r;
}
__device__ __forceinline__ ushort4 packbf(f32x4 a) {
    ushort4 u; u.x = f2bf(a[0]); u.y = f2bf(a[1]); u.z = f2bf(a[2]); u.w = f2bf(a[3]);
    return u;
}

// ---------------------------------------------------------------------------
// k_prep: weights -> bf16; conv weight reordered (n,kw) -> (kw,n).
// ---------------------------------------------------------------------------
__global__ __launch_bounds__(256) void k_prep(const float* __restrict__ W1,
                                              const float* __restrict__ W2,
                                              const float* __restrict__ cw,
                                              u16* __restrict__ W1b,
                                              u16* __restrict__ W2b,
                                              u16* __restrict__ Wcb) {
    const int i0 = blockIdx.x * 256 + threadIdx.x, stp = gridDim.x * 256;
    for (int i = i0; i < HH * SS; i += stp) W1b[i] = f2bf(W1[i]);
    for (int i = i0; i < SS * HH; i += stp) W2b[i] = f2bf(W2[i]);
    for (int i = i0; i < HH * 192; i += stp) {
        int h = i / 192, q = i % 192, n = q / 3, kw = q % 3;
        Wcb[h * 192 + kw * 64 + n] = f2bf(cw[i]);
    }
}

// ---------------------------------------------------------------------------
// k_gcn: one block per graph; everything through H2 stays in LDS (round-6
// structure minus conv). Barrier-free hidden-chunk loop (wave-private rows).
//   phase0: adjacency Asm (f32, LDS atomics) -> As bf16 [64 n][72]
//   MFMA0 : Gs[node][s] = (X @ A^T)^T
//   loop hc=0..7: MFMA1 H1c[node][h]=relu(W1c@G^T)^T ; MFMA2 accT += H1c@W2c^T
//   MFMA3 : H2T[s][n] = (A @ T)^T + b2  -> global bf16 (12 KB/graph)
// LDS: As@0(9216) Gs@9216(13312) H1c@22528(9216) Ts@31744(13824);
//      Asm f32[4096]@29696 (dead before H1c tail/Ts use); deg@0,dinv@256.
// ---------------------------------------------------------------------------
__global__ __launch_bounds__(256) void k_gcn(const float* __restrict__ x,
                                             const int* __restrict__ ei,
                                             const u16* __restrict__ W1b,
                                             const float* __restrict__ b1,
                                             const u16* __restrict__ W2b,
                                             const float* __restrict__ b2,
                                             u16* __restrict__ H2T) {
    const int b = blockIdx.x, t = threadIdx.x;
    const int w = t >> 6, lane = t & 63, quad = lane >> 4, l16 = lane & 15;

    __shared__ __align__(16) char smem[46080];
    u16*   As   = (u16*)smem;
    u16*   Gs   = (u16*)(smem + 9216);
    u16*   H1c  = (u16*)(smem + 22528);
    u16*   Ts   = (u16*)(smem + 31744);
    float* Asm  = (float*)(smem + 29696);   // 16 KB, phase-0 only
    int*   deg  = (int*)smem;
    float* dinv = (float*)(smem + 256);

    // ---- phase 0: normalized adjacency ----
    for (int i = t; i < 4096; i += 256) Asm[i] = 0.f;
    if (t < 64) deg[t] = 1;                         // self loop
    __syncthreads();
    const int* eb = ei + (size_t)b * 2 * EE;
    for (int e = t; e < EE; e += 256) atomicAdd(&deg[eb[EE + e]], 1);
    __syncthreads();
    if (t < 64) dinv[t] = rsqrtf((float)deg[t]);
    __syncthreads();
    for (int e = t; e < EE; e += 256) {
        int s = eb[e], d = eb[EE + e];
        atomicAdd(&Asm[d * 64 + s], dinv[s] * dinv[d]);
    }
    if (t < 64) atomicAdd(&Asm[t * 64 + t], dinv[t] * dinv[t]);
    __syncthreads();
    // As bf16 [64][72] (overwrites deg/dinv - dead)
    for (int i = t; i < 1024; i += 256) {
        int n = i >> 4, m4 = (i & 15) * 4;
        f32x4 v = *(const f32x4*)(Asm + n * 64 + m4);
        *(ushort4*)(As + n * 72 + m4) = packbf(v);
    }
    __syncthreads();

    // ---- MFMA0: Gs[node][s] ----
    {
        short8 bf0[2];
        #pragma unroll
        for (int kc = 0; kc < 2; ++kc)
            bf0[kc] = ld8bf(As + (w * 16 + l16) * 72 + kc * 32 + quad * 8);
        const float* xb = x + (size_t)b * SS * NN;
        #pragma unroll
        for (int j = 0; j < 6; ++j) {
            f32x4 acc = (f32x4){0.f, 0.f, 0.f, 0.f};
            #pragma unroll
            for (int kc = 0; kc < 2; ++kc) {
                short8 a = cvt8(xb + (j * 16 + l16) * 64 + kc * 32 + quad * 8);
                acc = __builtin_amdgcn_mfma_f32_16x16x32_bf16(a, bf0[kc], acc, 0, 0, 0);
            }
            *(ushort4*)(Gs + (w * 16 + l16) * 104 + j * 16 + quad * 4) = packbf(acc);
        }
    }
    // Gs/H1c rows wave-private -> no barriers through the chunk loop.

    f32x4 accT[6];
    #pragma unroll
    for (int j = 0; j < 6; ++j) accT[j] = (f32x4){0.f, 0.f, 0.f, 0.f};

    for (int hc = 0; hc < 8; ++hc) {
        short8 gb[3];
        #pragma unroll
        for (int kc = 0; kc < 3; ++kc)
            gb[kc] = ld8bf(Gs + (w * 16 + l16) * 104 + kc * 32 + quad * 8);
        // MFMA1: C[h][node] -> H1c[node][h]
        #pragma unroll
        for (int hs = 0; hs < 4; ++hs) {
            f32x4 a1 = (f32x4){0.f, 0.f, 0.f, 0.f};
            #pragma unroll
            for (int kc = 0; kc < 3; ++kc) {
                short8 wa = ld8bf(W1b + (size_t)(hc * 64 + hs * 16 + l16) * 96 + kc * 32 + quad * 8);
                a1 = __builtin_amdgcn_mfma_f32_16x16x32_bf16(wa, gb[kc], a1, 0, 0, 0);
            }
            float4 bias = *(const float4*)(b1 + hc * 64 + hs * 16 + quad * 4);
            f32x4 r;
            r[0] = fmaxf(a1[0] + bias.x, 0.f); r[1] = fmaxf(a1[1] + bias.y, 0.f);
            r[2] = fmaxf(a1[2] + bias.z, 0.f); r[3] = fmaxf(a1[3] + bias.w, 0.f);
            *(ushort4*)(H1c + (w * 16 + l16) * 72 + hs * 16 + quad * 4) = packbf(r);
        }
        // MFMA2: accT[node][s] += H1c @ W2c^T
        short8 ha[2];
        #pragma unroll
        for (int kc = 0; kc < 2; ++kc)
            ha[kc] = ld8bf(H1c + (w * 16 + l16) * 72 + kc * 32 + quad * 8);
        #pragma unroll
        for (int j = 0; j < 6; ++j)
            #pragma unroll
            for (int kc = 0; kc < 2; ++kc) {
                short8 wb = ld8bf(W2b + (size_t)(j * 16 + l16) * HH + hc * 64 + kc * 32 + quad * 8);
                accT[j] = __builtin_amdgcn_mfma_f32_16x16x32_bf16(ha[kc], wb, accT[j], 0, 0, 0);
            }
    }

    // ---- Ts[s][m] <- accT ----
    #pragma unroll
    for (int j = 0; j < 6; ++j)
        *(ushort4*)(Ts + (j * 16 + l16) * 72 + w * 16 + quad * 4) = packbf(accT[j]);
    __syncthreads();

    // ---- MFMA3: H2T[s][n] = A @ T + b2 (global) ----
    {
        short8 af[2];
        #pragma unroll
        for (int kc = 0; kc < 2; ++kc)
            af[kc] = ld8bf(As + (w * 16 + l16) * 72 + kc * 32 + quad * 8);
        u16* Hb = H2T + (size_t)b * SS * NN;
        #pragma unroll
        for (int j = 0; j < 6; ++j) {
            f32x4 a3 = (f32x4){0.f, 0.f, 0.f, 0.f};
            #pragma unroll
            for (int kc = 0; kc < 2; ++kc) {
                short8 tb = ld8bf(Ts + (j * 16 + l16) * 72 + kc * 32 + quad * 8);
                a3 = __builtin_amdgcn_mfma_f32_16x16x32_bf16(af[kc], tb, a3, 0, 0, 0);
            }
            float bs = b2[j * 16 + l16];
            f32x4 r = {a3[0] + bs, a3[1] + bs, a3[2] + bs, a3[3] + bs};
            // col=l16 -> s=j*16+l16 ; rows n=w*16+quad*4+r
            *(ushort4*)(Hb + (j * 16 + l16) * NN + w * 16 + quad * 4) = packbf(r);
        }
    }
}

// ---------------------------------------------------------------------------
// k_conv: grid (4 h-quarters, B). Block: 128 h x whole graph; LDS = Hp only
// (14.1 KB -> 6+ blocks/CU, ~24 waves/CU). Wave w: 2 h-tiles of 16.
// y[h][s] = sum_{kw,n} Wcb[h][kw*64+n] * Hp[s+kw][n]; float4 stores.
// ---------------------------------------------------------------------------
__global__ __launch_bounds__(256, 6) void k_conv(const u16* __restrict__ H2T,
                                                 const u16* __restrict__ Wcb,
                                                 float* __restrict__ out) {
    const int hb = blockIdx.x, b = blockIdx.y, t = threadIdx.x;
    const int w = t >> 6, lane = t & 63, quad = lane >> 4, l16 = lane & 15;

    __shared__ __align__(16) u16 Hp[98 * 72];   // [sp=s+1][n], pad cols 64..71 unused

    const u16* Hsrc = H2T + (size_t)b * SS * NN;
    for (int i = t; i < 98 * 8; i += 256) {
        int sp = i >> 3, c8 = (i & 7) * 8;
        int s = (sp == 0) ? 95 : ((sp == 97) ? 0 : sp - 1);
        *(short8*)(Hp + sp * 72 + c8) = *(const short8*)(Hsrc + s * NN + c8);
    }
    __syncthreads();

    float* ob = out + (size_t)b * SS * HH;
    #pragma unroll
    for (int ht = 0; ht < 2; ++ht) {
        const int h0 = hb * 128 + w * 32 + ht * 16;
        short8 wa[6];
        #pragma unroll
        for (int kc = 0; kc < 6; ++kc)
            wa[kc] = ld8bf(Wcb + (size_t)(h0 + l16) * 192 + kc * 32 + quad * 8);
        #pragma unroll
        for (int j = 0; j < 6; ++j) {
            f32x4 acc = (f32x4){0.f, 0.f, 0.f, 0.f};
            #pragma unroll
            for (int kc = 0; kc < 6; ++kc) {
                int kw = kc >> 1, nb = (kc & 1) * 32;
                short8 hb8 = ld8bf(Hp + (j * 16 + l16 + kw) * 72 + nb + quad * 8);
                acc = __builtin_amdgcn_mfma_f32_16x16x32_bf16(wa[kc], hb8, acc, 0, 0, 0);
            }
            // col=l16 -> s=j*16+l16 ; rows h=h0+quad*4+r (float4 contiguous in h)
            float4 vv = {acc[0], acc[1], acc[2], acc[3]};
            *(float4*)(ob + (size_t)(j * 16 + l16) * HH + h0 + quad * 4) = vv;
        }
    }
}

// ---------------------------------------------------------------------------
extern "C" void kernel_launch(void* const* d_in, const int* in_sizes, int n_in,
                              void* d_out, int out_size, void* d_ws, size_t ws_size,
                              hipStream_t stream) {
    const float* x  = (const float*)d_in[0];
    const int*   ei = (const int*)d_in[1];
    const float* W1 = (const float*)d_in[2];
    const float* b1 = (const float*)d_in[3];
    const float* W2 = (const float*)d_in[4];
    const float* b2 = (const float*)d_in[5];
    const float* cw = (const float*)d_in[6];
    float* out = (float*)d_out;

    char* wsp = (char*)d_ws;                     // 6.4 MB total
    u16* H2T = (u16*)wsp;                        // 6,291,456 B
    u16* W1b = (u16*)(wsp + 6291456);            // 98,304 B
    u16* W2b = (u16*)(wsp + 6389760);            // 98,304 B
    u16* Wcb = (u16*)(wsp + 6488064);            // 196,608 B

    k_prep<<<96, 256, 0, stream>>>(W1, W2, cw, W1b, W2b, Wcb);
    k_gcn <<<BB, 256, 0, stream>>>(x, ei, W1b, b1, W2b, b2, H2T);
    dim3 gc(4, BB);
    k_conv<<<gc, 256, 0, stream>>>(H2T, Wcb, out);
}